// Round 8
// baseline (2480.950 us; speedup 1.0000x reference)
//
#include <hip/hip_runtime.h>
#include <hip/hip_bf16.h>

// Swin-V2 window attention, fused one-block-per-window. All I/O fp32.
// B=32, H=W=64, C=60, NH=6, hd=10, WS=7 -> pad 70, nw=10, 3200 windows x 49 tok.
//
// R8: register-blocking to halve LDS instruction count.
//  P2: 2 channels x half-tokens per thread (x broadcast feeds 8 FMAs, float2 out)
//  P4: 2 q-rows per thread (k/v row read serves both; single balanced pass)
//  launch_bounds(256,3): VGPR cap 170 (w regs 120 in P2, a[] 98 in P4).

#define WSZ 7
#define NT 49
#define CH 60
#define IMG 64
#define LOG100F 4.605170185988092f

__global__ __launch_bounds__(256, 3)
void swin_win_attn(const float* __restrict__ x,
                   const float* __restrict__ qkv_w,
                   const float* __restrict__ qkv_b,
                   const float* __restrict__ logit_scale,
                   const float* __restrict__ proj_w,
                   const float* __restrict__ proj_b,
                   float* __restrict__ out)
{
    __shared__ __align__(16) float s_x[NT * CH];     // [t][c]; aliased as s_out after P2
    __shared__ __align__(16) float s_q[6 * NT * 10];
    __shared__ __align__(16) float s_k[6 * NT * 10];
    __shared__ __align__(16) float s_v[6 * NT * 10]; // 47,040 B -> 3 blocks/CU

    const int tid  = threadIdx.x;
    const int lane = tid & 63;
    const int wv   = __builtin_amdgcn_readfirstlane(tid >> 6);
    const int w  = blockIdx.x;
    const int b  = w / 100;
    const int wy = (w / 10) % 10;
    const int wx = w % 10;
    const int row0 = wy * WSZ;
    const int col0 = wx * WSZ;

    // ---- Phase 1: stage x tile (49x60, rows 240B) ----
    for (int idx = tid; idx < NT * 15; idx += 256) {
        int t = idx / 15, m = idx - t * 15;
        int r  = row0 + t / WSZ;
        int cc = col0 + t % WSZ;
        float4 v = make_float4(0.f, 0.f, 0.f, 0.f);
        if (r < IMG && cc < IMG)
            v = reinterpret_cast<const float4*>(x + ((b * IMG + r) * IMG + cc) * CH)[m];
        *reinterpret_cast<float4*>(s_x + t * CH + 4 * m) = v;
    }
    __syncthreads();

    // ---- Phase 2: qkv. thread = (channel-pair, token-half); 180 slots.
    //      2 weight rows in 120 VGPRs; x via same-address LDS b128 broadcast. ----
    if (tid < 180) {
        const int half = tid / 90;
        const int cp   = tid - 90 * half;
        const int c0   = 2 * cp;                 // even; pair never crosses part/head
        const int part = c0 / 60;
        const int cl   = c0 - 60 * part;
        const int h = cl / 10, d = cl - 10 * (cl / 10);
        float4 w0[15], w1[15];
        const float4* wp0 = reinterpret_cast<const float4*>(qkv_w + c0 * CH);
        const float4* wp1 = reinterpret_cast<const float4*>(qkv_w + (c0 + 1) * CH);
        #pragma unroll
        for (int m = 0; m < 15; ++m) { w0[m] = wp0[m]; w1[m] = wp1[m]; }
        const float b0 = qkv_b[c0], b1 = qkv_b[c0 + 1];
        float* dst = (part == 0) ? s_q : (part == 1) ? s_k : s_v;
        const int t0 = half ? 25 : 0, t1 = half ? NT : 25;
        for (int t = t0; t < t1; ++t) {
            float a0 = b0, a1 = b1;
            const float4* xr = reinterpret_cast<const float4*>(s_x + t * CH);
            #pragma unroll
            for (int m = 0; m < 15; ++m) {
                float4 xv = xr[m];               // broadcast (1-2 addrs per wave)
                a0 += xv.x * w0[m].x + xv.y * w0[m].y + xv.z * w0[m].z + xv.w * w0[m].w;
                a1 += xv.x * w1[m].x + xv.y * w1[m].y + xv.z * w1[m].z + xv.w * w1[m].w;
            }
            *reinterpret_cast<float2*>(dst + (h * NT + t) * 10 + d) = make_float2(a0, a1);
        }
    }
    __syncthreads();

    // ---- Phase 3: L2-normalize q,k rows (clamp 1e-12) ----
    for (int item = tid; item < 2 * 6 * NT; item += 256) {
        int which = item / (6 * NT);
        int r = item - which * (6 * NT);
        float* p = (which == 0) ? (s_q + r * 10) : (s_k + r * 10);
        float ss = 0.f;
        #pragma unroll
        for (int d = 0; d < 10; ++d) ss += p[d] * p[d];
        float inv = 1.f / fmaxf(sqrtf(ss), 1e-12f);
        #pragma unroll
        for (int d = 0; d < 10; ++d) p[d] *= inv;
    }
    __syncthreads();

    // ---- Phase 4: attention; thread = (head, row-pair); 150 slots, one pass ----
    if (tid < 150) {
        const int h  = tid / 25;
        const int ii = tid - 25 * h;
        const int i0 = ii, i1 = ii + 25;
        const bool two = (i1 < NT);
        float scale = __expf(fminf(logit_scale[h], LOG100F));
        float q0[10], q1[10];
        {
            const float2* qp0 = reinterpret_cast<const float2*>(s_q + (h * NT + i0) * 10);
            const float2* qp1 = reinterpret_cast<const float2*>(s_q + (h * NT + (two ? i1 : i0)) * 10);
            #pragma unroll
            for (int d = 0; d < 5; ++d) {
                float2 t0 = qp0[d]; q0[2*d] = t0.x; q0[2*d+1] = t0.y;
                float2 t1 = qp1[d]; q1[2*d] = t1.x; q1[2*d+1] = t1.y;
            }
        }
        float a0c[NT], a1c[NT];
        const float2* kb = reinterpret_cast<const float2*>(s_k + h * NT * 10);
        #pragma unroll
        for (int j = 0; j < NT; ++j) {
            const float2* kp = kb + j * 5;
            float2 k0 = kp[0], k1 = kp[1], k2 = kp[2], k3 = kp[3], k4 = kp[4];
            float dp0 = q0[0]*k0.x + q0[1]*k0.y + q0[2]*k1.x + q0[3]*k1.y
                      + q0[4]*k2.x + q0[5]*k2.y + q0[6]*k3.x + q0[7]*k3.y
                      + q0[8]*k4.x + q0[9]*k4.y;
            float dp1 = q1[0]*k0.x + q1[1]*k0.y + q1[2]*k1.x + q1[3]*k1.y
                      + q1[4]*k2.x + q1[5]*k2.y + q1[6]*k3.x + q1[7]*k3.y
                      + q1[8]*k4.x + q1[9]*k4.y;
            a0c[j] = dp0 * scale;
            a1c[j] = dp1 * scale;
        }
        float m0 = a0c[0], m1 = a1c[0];
        #pragma unroll
        for (int j = 1; j < NT; ++j) { m0 = fmaxf(m0, a0c[j]); m1 = fmaxf(m1, a1c[j]); }
        float s0 = 0.f, s1 = 0.f;
        #pragma unroll
        for (int j = 0; j < NT; ++j) {
            float e0 = __expf(a0c[j] - m0); a0c[j] = e0; s0 += e0;
            float e1 = __expf(a1c[j] - m1); a1c[j] = e1; s1 += e1;
        }
        float o0[10], o1[10];
        #pragma unroll
        for (int d = 0; d < 10; ++d) { o0[d] = 0.f; o1[d] = 0.f; }
        const float2* vb = reinterpret_cast<const float2*>(s_v + h * NT * 10);
        #pragma unroll
        for (int j = 0; j < NT; ++j) {
            const float2* vp = vb + j * 5;
            float2 v0 = vp[0], v1 = vp[1], v2 = vp[2], v3 = vp[3], v4 = vp[4];
            float aj0 = a0c[j], aj1 = a1c[j];
            o0[0] += aj0*v0.x; o0[1] += aj0*v0.y; o0[2] += aj0*v1.x; o0[3] += aj0*v1.y;
            o0[4] += aj0*v2.x; o0[5] += aj0*v2.y; o0[6] += aj0*v3.x; o0[7] += aj0*v3.y;
            o0[8] += aj0*v4.x; o0[9] += aj0*v4.y;
            o1[0] += aj1*v0.x; o1[1] += aj1*v0.y; o1[2] += aj1*v1.x; o1[3] += aj1*v1.y;
            o1[4] += aj1*v2.x; o1[5] += aj1*v2.y; o1[6] += aj1*v3.x; o1[7] += aj1*v3.y;
            o1[8] += aj1*v4.x; o1[9] += aj1*v4.y;
        }
        float inv0 = 1.f / s0, inv1 = 1.f / s1;
        {
            float* op0 = s_x + i0 * CH + h * 10;     // s_out aliases s_x
            #pragma unroll
            for (int d = 0; d < 5; ++d)
                *reinterpret_cast<float2*>(op0 + 2*d) =
                    make_float2(o0[2*d] * inv0, o0[2*d+1] * inv0);
            if (two) {
                float* op1 = s_x + i1 * CH + h * 10;
                #pragma unroll
                for (int d = 0; d < 5; ++d)
                    *reinterpret_cast<float2*>(op1 + 2*d) =
                        make_float2(o1[2*d] * inv1, o1[2*d+1] * inv1);
            }
        }
    }
    __syncthreads();

    // ---- Phase 5: proj. lane<60 = out channel, W-row in regs, tokens over waves ----
    if (lane < 60) {
        float4 w4[15];
        const float4* wp = reinterpret_cast<const float4*>(proj_w + lane * CH);
        #pragma unroll
        for (int m = 0; m < 15; ++m) w4[m] = wp[m];
        const float bias = proj_b[lane];
        for (int t = wv; t < NT; t += 4) {
            int r  = row0 + t / WSZ;
            int cc = col0 + t % WSZ;
            float a = bias;
            const float4* xr = reinterpret_cast<const float4*>(s_x + t * CH);
            #pragma unroll
            for (int m = 0; m < 15; ++m) {
                float4 xv = xr[m];                    // broadcast
                a += xv.x * w4[m].x + xv.y * w4[m].y
                   + xv.z * w4[m].z + xv.w * w4[m].w;
            }
            if (r < IMG && cc < IMG)
                out[((b * IMG + r) * IMG + cc) * CH + lane] = a;   // coalesced
        }
    }
}

extern "C" void kernel_launch(void* const* d_in, const int* in_sizes, int n_in,
                              void* d_out, int out_size, void* d_ws, size_t ws_size,
                              hipStream_t stream) {
    hipLaunchKernelGGL(swin_win_attn, dim3(3200), dim3(256), 0, stream,
                       (const float*)d_in[0], (const float*)d_in[1],
                       (const float*)d_in[2], (const float*)d_in[3],
                       (const float*)d_in[4], (const float*)d_in[5],
                       (float*)d_out);
}

// Round 9
// 255.230 us; speedup vs baseline: 9.7204x; 9.7204x over previous
//
#include <hip/hip_runtime.h>
#include <hip/hip_bf16.h>

// Swin-V2 window attention, fused one-block-per-window. All I/O fp32.
// B=32, H=W=64, C=60, NH=6, hd=10, WS=7 -> pad 70, nw=10, 3200 windows x 49 tok.
//
// R9: R7 phase shapes (single channel/thread, no register blocking — R8's 2x
// blocking spilled 5.8 GB of scratch) with:
//  - 384-thread blocks, LDS 51.7 KB -> 3 blocks/CU = 18 waves (was 12)
//  - k/v rows stride 12 (48B) read as 3x ds_read_b128 (was 5x b64)
//  - P3 normalizes k only; q normalized in-register inside P4
//  - launch_bounds(384,5): VGPR cap 102, est ~90 live (spill-safe)

#define WSZ 7
#define NT 49
#define CH 60
#define IMG 64
#define LOG100F 4.605170185988092f

__global__ __launch_bounds__(384, 5)
void swin_win_attn(const float* __restrict__ x,
                   const float* __restrict__ qkv_w,
                   const float* __restrict__ qkv_b,
                   const float* __restrict__ logit_scale,
                   const float* __restrict__ proj_w,
                   const float* __restrict__ proj_b,
                   float* __restrict__ out)
{
    __shared__ __align__(16) float s_x[NT * CH];      // 2940 f; aliased as s_out after P2
    __shared__ __align__(16) float s_q[6 * NT * 10];  // 2940 f, stride-10 rows
    __shared__ __align__(16) float s_k[6 * NT * 12];  // 3528 f, 48B rows (b128 x3)
    __shared__ __align__(16) float s_v[6 * NT * 12];  // 3528 f  => 51,744 B total

    const int tid  = threadIdx.x;
    const int lane = tid & 63;
    const int wv   = __builtin_amdgcn_readfirstlane(tid >> 6);
    const int w  = blockIdx.x;
    const int b  = w / 100;
    const int wy = (w / 10) % 10;
    const int wx = w % 10;
    const int row0 = wy * WSZ;
    const int col0 = wx * WSZ;

    // ---- Phase 1: stage x tile (49x60, rows 240B) + zero k/v pad words ----
    for (int idx = tid; idx < NT * 15; idx += 384) {
        int t = idx / 15, m = idx - t * 15;
        int r  = row0 + t / WSZ;
        int cc = col0 + t % WSZ;
        float4 v = make_float4(0.f, 0.f, 0.f, 0.f);
        if (r < IMG && cc < IMG)
            v = reinterpret_cast<const float4*>(x + ((b * IMG + r) * IMG + cc) * CH)[m];
        *reinterpret_cast<float4*>(s_x + t * CH + 4 * m) = v;
    }
    for (int idx = tid; idx < 2 * 6 * NT; idx += 384) {  // 588 pad pairs
        int r = idx >> 1, p = idx & 1;
        s_k[r * 12 + 10 + p] = 0.f;
        s_v[r * 12 + 10 + p] = 0.f;
    }
    __syncthreads();

    // ---- Phase 2: qkv. thread = (channel, token-half); 360 slots of 384.
    //      One 60-float weight row in VGPRs; x via same-address LDS b128. ----
    if (tid < 360) {
        const int c    = tid % 180;
        const int half = tid / 180;
        const int part = c / 60;
        const int cl   = c - 60 * part;
        const int h = cl / 10, d = cl - 10 * (cl / 10);
        float4 w4[15];
        const float4* wp = reinterpret_cast<const float4*>(qkv_w + c * CH);
        #pragma unroll
        for (int m = 0; m < 15; ++m) w4[m] = wp[m];
        const float bias = qkv_b[c];
        const int t0 = half ? 25 : 0, t1 = half ? NT : 25;
        for (int t = t0; t < t1; ++t) {
            float a = bias;
            const float4* xr = reinterpret_cast<const float4*>(s_x + t * CH);
            #pragma unroll
            for (int m = 0; m < 15; ++m) {
                float4 xv = xr[m];               // broadcast (<=2 addrs per wave)
                a += xv.x * w4[m].x + xv.y * w4[m].y + xv.z * w4[m].z + xv.w * w4[m].w;
            }
            if (part == 0)      s_q[(h * NT + t) * 10 + d] = a;
            else if (part == 1) s_k[(h * NT + t) * 12 + d] = a;
            else                s_v[(h * NT + t) * 12 + d] = a;
        }
    }
    __syncthreads();

    // ---- Phase 3: L2-normalize k rows only (q normalized inside P4) ----
    if (tid < 6 * NT) {
        float* p = s_k + tid * 12;
        float ss = 0.f;
        #pragma unroll
        for (int d = 0; d < 10; ++d) ss += p[d] * p[d];
        float inv = 1.f / fmaxf(sqrtf(ss), 1e-12f);
        #pragma unroll
        for (int d = 0; d < 10; ++d) p[d] *= inv;
    }
    __syncthreads();

    // ---- Phase 4: attention; thread = (head,row); 294 slots, one pass ----
    if (tid < 6 * NT) {
        const int h = tid / NT, i = tid - h * NT;
        float scale = __expf(fminf(logit_scale[h], LOG100F));
        float q[10];
        {
            const float2* qp = reinterpret_cast<const float2*>(s_q + tid * 10);
            #pragma unroll
            for (int d = 0; d < 5; ++d) { float2 t2 = qp[d]; q[2*d] = t2.x; q[2*d+1] = t2.y; }
            float ss = 0.f;
            #pragma unroll
            for (int d = 0; d < 10; ++d) ss += q[d] * q[d];
            float inv = scale / fmaxf(sqrtf(ss), 1e-12f);  // fold scale into q
            #pragma unroll
            for (int d = 0; d < 10; ++d) q[d] *= inv;
        }
        float a[NT];
        const float4* kb = reinterpret_cast<const float4*>(s_k + h * NT * 12);
        #pragma unroll
        for (int j = 0; j < NT; ++j) {
            float4 k0 = kb[j * 3 + 0];
            float4 k1 = kb[j * 3 + 1];
            float4 k2 = kb[j * 3 + 2];   // .z,.w zeroed pads
            a[j] = q[0]*k0.x + q[1]*k0.y + q[2]*k0.z + q[3]*k0.w
                 + q[4]*k1.x + q[5]*k1.y + q[6]*k1.z + q[7]*k1.w
                 + q[8]*k2.x + q[9]*k2.y;
        }
        float m = a[0];
        #pragma unroll
        for (int j = 1; j < NT; ++j) m = fmaxf(m, a[j]);
        float s = 0.f;
        #pragma unroll
        for (int j = 0; j < NT; ++j) { float e = __expf(a[j] - m); a[j] = e; s += e; }
        float o[10];
        #pragma unroll
        for (int d = 0; d < 10; ++d) o[d] = 0.f;
        const float4* vb = reinterpret_cast<const float4*>(s_v + h * NT * 12);
        #pragma unroll
        for (int j = 0; j < NT; ++j) {
            float4 v0 = vb[j * 3 + 0];
            float4 v1 = vb[j * 3 + 1];
            float4 v2 = vb[j * 3 + 2];
            float aj = a[j];
            o[0] += aj * v0.x; o[1] += aj * v0.y; o[2] += aj * v0.z; o[3] += aj * v0.w;
            o[4] += aj * v1.x; o[5] += aj * v1.y; o[6] += aj * v1.z; o[7] += aj * v1.w;
            o[8] += aj * v2.x; o[9] += aj * v2.y;
        }
        float inv = 1.f / s;
        float* op = s_x + i * CH + h * 10;   // s_out aliases s_x
        #pragma unroll
        for (int d = 0; d < 5; ++d)
            *reinterpret_cast<float2*>(op + 2 * d) =
                make_float2(o[2*d] * inv, o[2*d+1] * inv);
    }
    __syncthreads();

    // ---- Phase 5: proj. lane<60 = out channel, W-row in regs, tokens over 6 waves ----
    if (lane < 60) {
        float4 w4[15];
        const float4* wp = reinterpret_cast<const float4*>(proj_w + lane * CH);
        #pragma unroll
        for (int m = 0; m < 15; ++m) w4[m] = wp[m];
        const float bias = proj_b[lane];
        for (int t = wv; t < NT; t += 6) {
            int r  = row0 + t / WSZ;
            int cc = col0 + t % WSZ;
            float a = bias;
            const float4* xr = reinterpret_cast<const float4*>(s_x + t * CH);
            #pragma unroll
            for (int m = 0; m < 15; ++m) {
                float4 xv = xr[m];                    // broadcast
                a += xv.x * w4[m].x + xv.y * w4[m].y
                   + xv.z * w4[m].z + xv.w * w4[m].w;
            }
            if (r < IMG && cc < IMG)
                out[((b * IMG + r) * IMG + cc) * CH + lane] = a;   // coalesced
        }
    }
}

extern "C" void kernel_launch(void* const* d_in, const int* in_sizes, int n_in,
                              void* d_out, int out_size, void* d_ws, size_t ws_size,
                              hipStream_t stream) {
    hipLaunchKernelGGL(swin_win_attn, dim3(3200), dim3(384), 0, stream,
                       (const float*)d_in[0], (const float*)d_in[1],
                       (const float*)d_in[2], (const float*)d_in[3],
                       (const float*)d_in[4], (const float*)d_in[5],
                       (float*)d_out);
}